// Round 12
// baseline (99.746 us; speedup 1.0000x reference)
//
#include <hip/hip_runtime.h>
#include <stdint.h>

// Bilateral filter denoiser: K=5, sigma_s=2.0, sigma_r=0.1, B=8,C=3,H=512,W=512, fp32.
// weight(dy,dx) = exp(-(n-c)^2/(2*0.1^2)) * exp(-(dx^2+dy^2)/8)
//              = exp2( RC*(n-c)^2 + L[r2] ),  r2 = (dy-2)^2+(dx-2)^2, L[r2] = -r2*log2(e)/8
// arg = fma(fma(RC,n,B), n, C0L); C-sets chained just-in-time (row order 2,1,3,0,4).
// exp2 = hardware v_exp_f32 (r9 all-SW and r10 hybrid both regressed).
//
// ROUND 12: NO LDS, NO BARRIER. Evidence: r6-r11 -- adding VALU work costs full price
// (r9/r10 regress ~proportionally) but removing work gains nothing (r11: -25% LDS
// instrs + zero bank conflicts = neutral). That signature = the block-wide serializer
// dominates, and the only one every variant kept is the stage->syncthreads(vmcnt(0)
// drain)->compute skeleton + LDS round-trip. The 10 KB/block row working set fits L1
// (32 KB/CU) easily -- LDS staging buys nothing the caches don't already provide.
// New structure: each thread loads its 5 rows x 12 words DIRECTLY from global
// (3 x dwordx4 per row via memcpy, 4B-aligned -- global loads allow it; L1/L2-served
// after first touch), all 15 loads issued up-front for memory-level parallelism, then
// the identical tap core. Waves fully independent: no barrier, no phase-aligned drain.
// y-reflect: per-row index remap. x-reflect: only 32 threads in the 2 border
// block-columns take a statically-unrolled scalar-reflect path (no runtime-indexed
// local arrays -- those go to scratch).
//
// 8 px/thread (four float2 halves -> v_pk_* packed fp32), 64x32 tile, 256 threads.
// ALL compute is MACROS: the inliner OUTLINES large [&]-capture lambdas at 24 call
// sites (capture struct in scratch, +200 MB HBM traffic -- rounds 3-4).
// __launch_bounds__(256,3): ~15 quads + coeffs ~ 130-150 VGPR, under the 170 cap.
// Center tap: weight == 1 exactly -> ws init 1, acc init c; ws>=1 so no clip, rcp ok.

#define KK 5
#define TX 64          // tile width (pixels)
#define TY 32          // tile height
#define PXT 8          // pixels per thread along x
#define IMG_H 512
#define IMG_W 512

typedef float v2f __attribute__((ext_vector_type(2)));
typedef float v4f __attribute__((ext_vector_type(4)));

#if defined(__has_builtin)
#if __has_builtin(__builtin_amdgcn_exp2f)
#define FAST_EXP2(x) __builtin_amdgcn_exp2f(x)
#else
#define FAST_EXP2(x) exp2f(x)
#endif
#if __has_builtin(__builtin_amdgcn_rcpf)
#define FAST_RCP(x) __builtin_amdgcn_rcpf(x)
#else
#define FAST_RCP(x) (1.0f / (x))
#endif
#else
#define FAST_EXP2(x) exp2f(x)
#define FAST_RCP(x) (1.0f / (x))
#endif

__device__ __forceinline__ int reflect_idx(int i, int n) {
    i = (i < 0) ? -i : i;
    i = (i >= n) ? (2 * n - 2 - i) : i;
    return i;
}

// ---- macro compute core (no function boundaries) ----
#define PKFMA(a, b, c) __builtin_elementwise_fma((a), (b), (c))

#define TAP(nA, nB, nC, nD, CA, CB, CC, CD) {                                   \
    v2f tA_ = PKFMA(PKFMA(RCv, (nA), BA), (nA), (CA));                          \
    v2f tB_ = PKFMA(PKFMA(RCv, (nB), BB), (nB), (CB));                          \
    v2f tC_ = PKFMA(PKFMA(RCv, (nC), BC), (nC), (CC));                          \
    v2f tD_ = PKFMA(PKFMA(RCv, (nD), BD), (nD), (CD));                          \
    v2f eA_, eB_, eC_, eD_;                                                     \
    eA_.x = FAST_EXP2(tA_.x); eA_.y = FAST_EXP2(tA_.y);                         \
    eB_.x = FAST_EXP2(tB_.x); eB_.y = FAST_EXP2(tB_.y);                         \
    eC_.x = FAST_EXP2(tC_.x); eC_.y = FAST_EXP2(tC_.y);                         \
    eD_.x = FAST_EXP2(tD_.x); eD_.y = FAST_EXP2(tD_.y);                         \
    wsA += eA_; wsB += eB_; wsC += eC_; wsD += eD_;                             \
    accA = PKFMA(eA_, (nA), accA);                                              \
    accB = PKFMA(eB_, (nB), accB);                                              \
    accC = PKFMA(eC_, (nC), accC);                                              \
    accD = PKFMA(eD_, (nD), accD);                                              \
}

// window words w0..w11 (quads Qa,Qb,Qc); pixels = w2..w9.
// even pairs Pk=(w2k,w2k+1) k=0..5; odd pairs Rk=(w2k+1,w2k+2) k=0..4.
//  dx0:(P0..P3)  dx1:(R0..R3)  dx2:(P1..P4)  dx3:(R1..R4)  dx4:(P2..P5)
#define DOROW(Qa, Qb, Qc, CaA,CaB,CaC,CaD, CbA,CbB,CbC,CbD, CcA,CcB,CcC,CcD, CENTER) { \
    v2f P0_ = {Qa[0], Qa[1]};                                                   \
    v2f P1_ = {Qa[2], Qa[3]};                                                   \
    v2f P2_ = {Qb[0], Qb[1]};                                                   \
    v2f P3_ = {Qb[2], Qb[3]};                                                   \
    v2f P4_ = {Qc[0], Qc[1]};                                                   \
    v2f P5_ = {Qc[2], Qc[3]};                                                   \
    v2f R0_ = {Qa[1], Qa[2]};                                                   \
    v2f R1_ = {Qa[3], Qb[0]};                                                   \
    v2f R2_ = {Qb[1], Qb[2]};                                                   \
    v2f R3_ = {Qb[3], Qc[0]};                                                   \
    v2f R4_ = {Qc[1], Qc[2]};                                                   \
    TAP(P0_, P1_, P2_, P3_, CaA, CaB, CaC, CaD);          /* dx = 0 */          \
    TAP(R0_, R1_, R2_, R3_, CbA, CbB, CbC, CbD);          /* dx = 1 */          \
    if (!(CENTER)) TAP(P1_, P2_, P3_, P4_, CcA, CcB, CcC, CcD); /* dx = 2 */    \
    TAP(R1_, R2_, R3_, R4_, CbA, CbB, CbC, CbD);          /* dx = 3 */          \
    TAP(P2_, P3_, P4_, P5_, CaA, CaB, CaC, CaD);          /* dx = 4 */          \
}

// direct-from-global row load: 12 words [xbase, xbase+12) of reflected row (oy+dy-2).
// interior threads: three 16B loads (4B-aligned, global_load_dwordx4).
// border threads (32 per border block only): statically-unrolled scalar reflect loads.
#define LOADR(dy, Qa, Qb, Qc) {                                                 \
    int gy_ = reflect_idx(oy + (dy) - 2, IMG_H);                                \
    const float* r_ = src + gy_ * IMG_W;                                        \
    if (interior) {                                                             \
        __builtin_memcpy(&Qa, r_ + xbase, 16);                                  \
        __builtin_memcpy(&Qb, r_ + xbase + 4, 16);                              \
        __builtin_memcpy(&Qc, r_ + xbase + 8, 16);                              \
    } else {                                                                    \
        Qa[0] = r_[reflect_idx(xbase + 0, IMG_W)];                              \
        Qa[1] = r_[reflect_idx(xbase + 1, IMG_W)];                              \
        Qa[2] = r_[reflect_idx(xbase + 2, IMG_W)];                              \
        Qa[3] = r_[reflect_idx(xbase + 3, IMG_W)];                              \
        Qb[0] = r_[reflect_idx(xbase + 4, IMG_W)];                              \
        Qb[1] = r_[reflect_idx(xbase + 5, IMG_W)];                              \
        Qb[2] = r_[reflect_idx(xbase + 6, IMG_W)];                              \
        Qb[3] = r_[reflect_idx(xbase + 7, IMG_W)];                              \
        Qc[0] = r_[reflect_idx(xbase + 8, IMG_W)];                              \
        Qc[1] = r_[reflect_idx(xbase + 9, IMG_W)];                              \
        Qc[2] = r_[reflect_idx(xbase + 10, IMG_W)];                             \
        Qc[3] = r_[reflect_idx(xbase + 11, IMG_W)];                             \
    }                                                                           \
}

__global__ __launch_bounds__(256, 3)
void bilateral_kernel(const float* __restrict__ x, float* __restrict__ out) {
    const int tid = threadIdx.x;
    const int tileX0 = blockIdx.x * TX;
    const int tileY0 = blockIdx.y * TY;
    const int img = blockIdx.z;
    const float* __restrict__ src = x + (size_t)img * (IMG_H * IMG_W);
    float* __restrict__ dst = out + (size_t)img * (IMG_H * IMG_W);

    const int txg = tid & 7;       // thread x-group: 0..7
    const int ty  = tid >> 3;      // thread row:     0..31
    const int ox  = tileX0 + txg * PXT;
    const int oy  = tileY0 + ty;
    const int xbase = ox - 2;      // first word of this thread's 12-word window
    const bool interior = (xbase >= 0) && (xbase + 12 <= IMG_W);

    const float RC = -72.13475204444817f;        // -1/(2*0.1^2) * log2(e)
    // L[r2] = -r2 * log2(e)/8 = r2 * L1
    const float L1 = -0.18033688011112043f;
    const float L4 = -0.7213475204444817f;
    const v2f RCv = {RC, RC};

    // ---- issue all 15 row-quad loads up-front (max memory-level parallelism) ----
    v4f Q2a, Q2b, Q2c, Q1a, Q1b, Q1c, Q3a, Q3b, Q3c, Q0a, Q0b, Q0c, Q4a, Q4b, Q4c;
    LOADR(2, Q2a, Q2b, Q2c);
    LOADR(1, Q1a, Q1b, Q1c);
    LOADR(3, Q3a, Q3b, Q3c);
    LOADR(0, Q0a, Q0b, Q0c);
    LOADR(4, Q4a, Q4b, Q4c);

    // center row (dy=2): pixels are words +2..+9
    const v2f cA = {Q2a[2], Q2a[3]};
    const v2f cB = {Q2b[0], Q2b[1]};
    const v2f cC = {Q2b[2], Q2b[3]};
    const v2f cD = {Q2c[0], Q2c[1]};

    // per-pixel exponent-poly coefficients: arg = RC*n^2 + B*n + (C0 + L[r2])
    const v2f BA = cA * (-2.0f * RC);
    const v2f BB = cB * (-2.0f * RC);
    const v2f BC = cC * (-2.0f * RC);
    const v2f BD = cD * (-2.0f * RC);
    v2f C0A = (cA * cA) * RC;
    v2f C0B = (cB * cB) * RC;
    v2f C0C = (cC * cC) * RC;
    v2f C0D = (cD * cD) * RC;
    const v2f C1A = C0A + L1, C1B = C0B + L1, C1C = C0C + L1, C1D = C0D + L1;
    const v2f C4A = C0A + L4, C4B = C0B + L4, C4C = C0C + L4, C4D = C0D + L4;

    // center tap folded in: weight exactly 1
    v2f wsA = {1.0f, 1.0f}, wsB = {1.0f, 1.0f}, wsC = {1.0f, 1.0f}, wsD = {1.0f, 1.0f};
    v2f accA = cA, accB = cB, accC = cC, accD = cD;

    // dy = 2 first: r2 = {4,1,-,1,4}
    DOROW(Q2a, Q2b, Q2c,
          C4A, C4B, C4C, C4D, C1A, C1B, C1C, C1D, C1A, C1B, C1C, C1D, true);

    // dy = 1,3 need C5 = C4+L1, C2 = C1+L1  (L5 = L4+L1, L2 = 2*L1)
    const v2f C5A = C4A + L1, C5B = C4B + L1, C5C = C4C + L1, C5D = C4D + L1;
    const v2f C2A = C1A + L1, C2B = C1B + L1, C2C = C1C + L1, C2D = C1D + L1;
    DOROW(Q1a, Q1b, Q1c,
          C5A, C5B, C5C, C5D, C2A, C2B, C2C, C2D, C1A, C1B, C1C, C1D, false);
    DOROW(Q3a, Q3b, Q3c,
          C5A, C5B, C5C, C5D, C2A, C2B, C2C, C2D, C1A, C1B, C1C, C1D, false);
    // C1, C2 dead. dy = 0,4 need C8 = C4+L4  (L8 = 2*L4)
    const v2f C8A = C4A + L4, C8B = C4B + L4, C8C = C4C + L4, C8D = C4D + L4;
    DOROW(Q0a, Q0b, Q0c,
          C8A, C8B, C8C, C8D, C5A, C5B, C5C, C5D, C4A, C4B, C4C, C4D, false);
    DOROW(Q4a, Q4b, Q4c,
          C8A, C8B, C8C, C8D, C5A, C5B, C5C, C5D, C4A, C4B, C4C, C4D, false);

    float* drow = &dst[oy * IMG_W + ox];
    float4 o0, o1;
    o0.x = accA.x * FAST_RCP(wsA.x);   // ws >= 1 (center tap), clip(1e-10) is dead
    o0.y = accA.y * FAST_RCP(wsA.y);
    o0.z = accB.x * FAST_RCP(wsB.x);
    o0.w = accB.y * FAST_RCP(wsB.y);
    o1.x = accC.x * FAST_RCP(wsC.x);
    o1.y = accC.y * FAST_RCP(wsC.y);
    o1.z = accD.x * FAST_RCP(wsD.x);
    o1.w = accD.y * FAST_RCP(wsD.y);
    *reinterpret_cast<float4*>(drow) = o0;
    *reinterpret_cast<float4*>(drow + 4) = o1;
}

extern "C" void kernel_launch(void* const* d_in, const int* in_sizes, int n_in,
                              void* d_out, int out_size, void* d_ws, size_t ws_size,
                              hipStream_t stream) {
    const float* x = (const float*)d_in[0];
    // d_in[1] (spatial 5x5) is analytically exp(-(dx^2+dy^2)/8); folded into constants.
    float* out = (float*)d_out;

    const int n_img = out_size / (IMG_H * IMG_W);   // B*C = 24
    dim3 grid(IMG_W / TX, IMG_H / TY, n_img);       // (8, 16, 24)
    dim3 block(256);
    hipLaunchKernelGGL(bilateral_kernel, grid, block, 0, stream, x, out);
}